// Round 5
// baseline (1863.658 us; speedup 1.0000x reference)
//
#include <hip/hip_runtime.h>
#include <cstdint>
#include <cstddef>

// Problem shape (fixed by the reference): E=1.6M, D=64, H=128, N=100k.
#define D_FEAT 64
#define H_HID 128

// Bucket sort parameters: 256 nodes per bucket -> 391 buckets; mean bucket
// size 2E*256/N = 8192 entries. The fused aggregate kernel streams entries
// from global; buckets need no LDS cap.
#define NBK_SHIFT 8
#define NBK_MASK 255
#define MAXBKT 512      // histogram width (>= nbkt = 391)
#define TILE 8192       // edges per workgroup tile in count/scatter passes
#define FSTRIDE 68      // sFlow row stride in floats (272B): breaks the
                        // 256B-stride same-bank pattern on phase-B x-loads

// ---------------------------------------------------------------------------
// Workspace: bktCnt[512], bktOff[512], bktCur[512], gbkt[2E]
// (packed (localnode<<21)|edge). flow never touches HBM: it lives in LDS of
// the fused aggregate+MLP kernel.
// ---------------------------------------------------------------------------

// 1. Coarse histogram: LDS-privatized counts, ~391 global atomics per tile.
__global__ __launch_bounds__(1024) void bktcount_kernel(
    const int* __restrict__ idx, int* __restrict__ bktCnt, int twoE) {
  __shared__ int cnt[MAXBKT];
  if (threadIdx.x < MAXBKT) cnt[threadIdx.x] = 0;
  __syncthreads();
  int base = blockIdx.x * TILE;
#pragma unroll
  for (int k = 0; k < TILE / 1024; ++k) {
    int t = base + k * 1024 + threadIdx.x;
    if (t < twoE) atomicAdd(&cnt[idx[t] >> NBK_SHIFT], 1);
  }
  __syncthreads();
  if (threadIdx.x < MAXBKT) {
    int c = cnt[threadIdx.x];
    if (c) atomicAdd(&bktCnt[threadIdx.x], c);
  }
}

// 2. Exclusive scan of the bucket counts; also seeds the atomic cursors.
__global__ __launch_bounds__(512) void bktscan_kernel(
    const int* __restrict__ bktCnt, int* __restrict__ bktOff,
    int* __restrict__ bktCur, int nbkt) {
  __shared__ int s[MAXBKT];
  int v = (threadIdx.x < nbkt) ? bktCnt[threadIdx.x] : 0;
  s[threadIdx.x] = v;
  __syncthreads();
  for (int d = 1; d < MAXBKT; d <<= 1) {
    int t = (threadIdx.x >= d) ? s[threadIdx.x - d] : 0;
    __syncthreads();
    s[threadIdx.x] += t;
    __syncthreads();
  }
  if (threadIdx.x < nbkt) {
    int e = s[threadIdx.x] - v;
    bktOff[threadIdx.x] = e;
    bktCur[threadIdx.x] = e;
  }
}

// 3. Bucket scatter with LDS staging: rank edges per bucket in LDS, reserve
// one contiguous run per (tile,bucket) with a single global atomic, reorder
// bucket-grouped in LDS, stream out coalesced runs (~21 entries = 84B).
__global__ __launch_bounds__(1024) void bktscatter_kernel(
    const int* __restrict__ idx, int* __restrict__ bktCur,
    unsigned int* __restrict__ gbkt, int E, int twoE) {
  __shared__ int cnt[MAXBKT];
  __shared__ int lofs[MAXBKT];            // exclusive local offsets
  __shared__ int delta[MAXBKT];           // global runbase - lofs
  __shared__ unsigned int sval[TILE];     // packed (ln<<21)|e, bucket-grouped
  __shared__ unsigned short sbid[TILE];   // bucket id per staged slot

  if (threadIdx.x < MAXBKT) cnt[threadIdx.x] = 0;
  __syncthreads();

  int base = blockIdx.x * TILE;
  int myb[8], myr[8];
  unsigned int myv[8];
  int m = 0;
#pragma unroll
  for (int k = 0; k < 8; ++k) {
    int t = base + k * 1024 + threadIdx.x;
    if (t < twoE) {
      int node = idx[t];
      int b = node >> NBK_SHIFT;
      int e = (t < E) ? t : t - E;                      // edge id (< 2^21)
      myb[m] = b;
      myv[m] = ((unsigned int)(node & NBK_MASK) << 21) | (unsigned int)e;
      myr[m] = atomicAdd(&cnt[b], 1);                   // local rank
      ++m;
    }
  }
  __syncthreads();

  // Exclusive scan cnt -> lofs (512 lanes active; all 1024 hit barriers).
  {
    int v = (threadIdx.x < MAXBKT) ? cnt[threadIdx.x] : 0;
    if (threadIdx.x < MAXBKT) lofs[threadIdx.x] = v;
    __syncthreads();
    for (int d = 1; d < MAXBKT; d <<= 1) {
      int t = (threadIdx.x >= d && threadIdx.x < MAXBKT) ? lofs[threadIdx.x - d] : 0;
      __syncthreads();
      if (threadIdx.x < MAXBKT) lofs[threadIdx.x] += t;
      __syncthreads();
    }
    if (threadIdx.x < MAXBKT) lofs[threadIdx.x] -= v;   // exclusive
  }
  __syncthreads();

  // One global reservation per nonzero bucket.
  if (threadIdx.x < MAXBKT) {
    int c = cnt[threadIdx.x];
    int rb = c ? atomicAdd(&bktCur[threadIdx.x], c) : 0;
    delta[threadIdx.x] = rb - lofs[threadIdx.x];
  }
  __syncthreads();

  // Stage bucket-grouped.
  for (int k = 0; k < m; ++k) {
    int slot = lofs[myb[k]] + myr[k];
    sval[slot] = myv[k];
    sbid[slot] = (unsigned short)myb[k];
  }
  __syncthreads();

  // Stream out: consecutive slots -> consecutive global addrs within runs.
  int tot = min(TILE, twoE - base);
  for (int s = threadIdx.x; s < tot; s += 1024) {
    gbkt[delta[sbid[s]] + s] = sval[s];
  }
}

// ---------------------------------------------------------------------------
// 4. Fused aggregate + MLP: one WG per bucket (256 nodes).
//    Phase A: flow tile accumulated in LDS via ds_add_f32. Entries streamed
//      unsorted from gbkt; 16 lanes per entry pull the full 256B attr row.
//    Phase B: 4 lanes per node (q = lane&3), the proven spill-free mlp4
//      datapath, x read from the LDS flow tile. Lane q ends with
//      out[16q..16q+16) via static-index shfl_xor reduce-scatter:
//        reg r <-> global j = 32*((q>>1)^(r>>5)) | ((16(q&1)+(r&31))&31)
//    flow[] never touches HBM; bktsort/gather/mlp launches collapse to one.
//    LDS: 69.6KB flow (68f row stride: phase-B x-reads 2-way not 16-way) +
//         40KB sW1 (quarters at +40f -> banks 0/8/16/24) + 32.9KB sW2
//         (quarter stride 2056) + biases = 144.3KB -> 1 WG/CU, 16 waves.
// ---------------------------------------------------------------------------
__global__ __launch_bounds__(1024, 1) void agg_mlp_kernel(
    const int* __restrict__ bktCnt, const int* __restrict__ bktOff,
    const unsigned int* __restrict__ gbkt, const float* __restrict__ attr,
    const float* __restrict__ W1, const float* __restrict__ b1,
    const float* __restrict__ W2, const float* __restrict__ b2,
    float* __restrict__ out, int N) {
  __shared__ __align__(16) float sFlow[256 * FSTRIDE]; // 69632 B
  __shared__ __align__(16) float sW1[64 * 160];        // 40960 B
  __shared__ __align__(16) float sW2[4 * 2056];        // 32896 B
  __shared__ __align__(16) float sB1[H_HID];
  __shared__ __align__(16) float sB2[D_FEAT];

  // Weights -> LDS (L2/L3-resident after the first few WGs).
  for (int t = threadIdx.x; t < 64 * 128; t += 1024) {
    int i = t >> 7, k = t & 127;
    sW1[i * 160 + (k >> 5) * 40 + (k & 31)] = W1[t];
  }
  for (int t = threadIdx.x; t < 128 * 64; t += 1024) {
    int k = t >> 6, j = t & 63;
    sW2[(k >> 5) * 2056 + (k & 31) * 64 + j] = W2[t];
  }
  if (threadIdx.x < H_HID) sB1[threadIdx.x] = b1[threadIdx.x];
  if (threadIdx.x < D_FEAT) sB2[threadIdx.x] = b2[threadIdx.x];
  {
    float4 z = make_float4(0.f, 0.f, 0.f, 0.f);
    float4* f4 = reinterpret_cast<float4*>(sFlow);
    for (int v = threadIdx.x; v < (256 * FSTRIDE) / 4; v += 1024) f4[v] = z;
  }
  __syncthreads();

  int b = blockIdx.x;
  int base = bktOff[b];
  int sz = bktCnt[b];

  // ---- Phase A: LDS flow accumulation -------------------------------------
  {
    int grp = threadIdx.x >> 4;   // entry subgroup 0..63
    int l = threadIdx.x & 15;     // float4 slot within the 256B row
    for (int s = grp; s < sz; s += 64) {
      unsigned int v = gbkt[base + s];
      int ln = v >> 21;                         // local node 0..255
      int e = (int)(v & 0x1FFFFFu);             // edge id
      float4 a = reinterpret_cast<const float4*>(attr)[(size_t)e * 16 + l];
      float* dst = &sFlow[ln * FSTRIDE + l * 4];
      atomicAdd(dst + 0, a.x);
      atomicAdd(dst + 1, a.y);
      atomicAdd(dst + 2, a.z);
      atomicAdd(dst + 3, a.w);
    }
  }
  __syncthreads();

  // ---- Phase B: MLP, 4 lanes per node -------------------------------------
  int ln = threadIdx.x >> 2;      // node within bucket
  int q = threadIdx.x & 3;        // k-quarter / j-slice
  int n = (b << NBK_SHIFT) + ln;
  if (n >= N) return;             // no barriers below

  const float* xrow = &sFlow[ln * FSTRIDE];

  float h[32];
  {
    const float4* b1q = reinterpret_cast<const float4*>(sB1 + (q << 5));
#pragma unroll
    for (int v = 0; v < 8; ++v) {
      float4 bb = b1q[v];
      h[4 * v + 0] = bb.x; h[4 * v + 1] = bb.y;
      h[4 * v + 2] = bb.z; h[4 * v + 3] = bb.w;
    }
  }
  const float* w1q = sW1 + q * 40;
  for (int ii = 0; ii < 16; ++ii) {
    float4 x4 = reinterpret_cast<const float4*>(xrow)[ii];
    const float* wr = w1q + (ii * 4) * 160;
#pragma unroll
    for (int u = 0; u < 4; ++u) {
      float xi = (u == 0) ? x4.x : (u == 1) ? x4.y : (u == 2) ? x4.z : x4.w;
      const float* w = wr + u * 160;
#pragma unroll
      for (int r = 0; r < 32; r += 4) {
        float4 w4 = *reinterpret_cast<const float4*>(w + r);
        h[r + 0] = fmaf(xi, w4.x, h[r + 0]);
        h[r + 1] = fmaf(xi, w4.y, h[r + 1]);
        h[r + 2] = fmaf(xi, w4.z, h[r + 2]);
        h[r + 3] = fmaf(xi, w4.w, h[r + 3]);
      }
    }
  }
#pragma unroll
  for (int r = 0; r < 32; ++r) h[r] = fmaxf(h[r], 0.f);

  float acc[64];
#pragma unroll
  for (int r = 0; r < 64; ++r) acc[r] = 0.f;

  const float* w2q = sW2 + q * 2056;
  int rot = (q & 1) << 4;
  int hi  = (q >> 1) << 5;

#pragma unroll
  for (int kl = 0; kl < 32; ++kl) {
    float hk = h[kl];
    const float* wr = w2q + kl * 64;
#pragma unroll
    for (int g = 0; g < 16; ++g) {
      int j = (hi ^ ((g >> 3) << 5)) | ((rot + ((g << 2) & 31)) & 31);
      float4 w4 = *reinterpret_cast<const float4*>(wr + j);
      acc[4 * g + 0] = fmaf(hk, w4.x, acc[4 * g + 0]);
      acc[4 * g + 1] = fmaf(hk, w4.y, acc[4 * g + 1]);
      acc[4 * g + 2] = fmaf(hk, w4.z, acc[4 * g + 2]);
      acc[4 * g + 3] = fmaf(hk, w4.w, acc[4 * g + 3]);
    }
  }

#pragma unroll
  for (int r = 0; r < 32; ++r) acc[r] += __shfl_xor(acc[32 + r], 2);
#pragma unroll
  for (int r = 0; r < 16; ++r) acc[r] += __shfl_xor(acc[16 + r], 1);

  float* orow = out + (size_t)n * D_FEAT + (q << 4);
  const float4* b2q = reinterpret_cast<const float4*>(sB2 + (q << 4));
#pragma unroll
  for (int v = 0; v < 4; ++v) {
    float4 bb = b2q[v];
    reinterpret_cast<float4*>(orow)[v] =
        make_float4(acc[4 * v + 0] + bb.x, acc[4 * v + 1] + bb.y,
                    acc[4 * v + 2] + bb.z, acc[4 * v + 3] + bb.w);
  }
}

// ---------------------------------------------------------------------------
// Launch
// ---------------------------------------------------------------------------
extern "C" void kernel_launch(void* const* d_in, const int* in_sizes, int n_in,
                              void* d_out, int out_size, void* d_ws, size_t ws_size,
                              hipStream_t stream) {
  const int*   edge_index = (const int*)d_in[0];    // [2, E]
  const float* edge_attr  = (const float*)d_in[1];  // [E, 64]
  const float* W1         = (const float*)d_in[3];  // [64, 128]
  const float* b1         = (const float*)d_in[4];  // [128]
  const float* W2         = (const float*)d_in[5];  // [128, 64]
  const float* b2         = (const float*)d_in[6];  // [64]
  float* out = (float*)d_out;

  const int E = in_sizes[1] / D_FEAT;   // 1,600,000
  const int N = out_size / D_FEAT;      // 100,000
  const int twoE = 2 * E;
  const int nbkt = (N + NBK_MASK) >> NBK_SHIFT;       // 391
  const int ntile = (twoE + TILE - 1) / TILE;         // 391

  int* bktCnt = (int*)d_ws;             // [512]
  int* bktOff = bktCnt + MAXBKT;        // [512]
  int* bktCur = bktOff + MAXBKT;        // [512]
  unsigned int* gbkt = (unsigned int*)(bktCur + MAXBKT);  // [2E]

  hipMemsetAsync(bktCnt, 0, MAXBKT * sizeof(int), stream);
  bktcount_kernel<<<ntile, 1024, 0, stream>>>(edge_index, bktCnt, twoE);
  bktscan_kernel<<<1, MAXBKT, 0, stream>>>(bktCnt, bktOff, bktCur, nbkt);
  bktscatter_kernel<<<ntile, 1024, 0, stream>>>(edge_index, bktCur, gbkt, E, twoE);
  agg_mlp_kernel<<<nbkt, 1024, 0, stream>>>(bktCnt, bktOff, gbkt, edge_attr,
                                            W1, b1, W2, b2, out, N);
}